// Round 11
// baseline (79.928 us; speedup 1.0000x reference)
//
#include <hip/hip_runtime.h>
#include <hip/hip_bf16.h>
#include <math.h>

// Problem constants (match reference)
#define B_ 16
#define L_ 256
#define A_ 128
#define D_ 4
#define H_ 64
#define DFF_ 256
#define PRED_ 64
#define COUT_ 8

// ws layout (floats)
// gate weights SoA, exp2-prescaled: [g][d][64], g=0:z (x L2E), g=1:h (x 2*L2E)
#define WS_GW   0
// gate biases, same prescale: [g][64]
#define WS_GB   512
#define WS_PART 640                       // [B*L][64] per-(b,l) agent-sums

#define L2E 1.4426950408889634f

typedef float v2 __attribute__((ext_vector_type(2)));

// ---------------------------------------------------------------------------
// Kernel 0: fold gate weights. Wg' = (W_g @ Lg_w[0:64,:]) * s_g, stored SoA
// [d][j]; bg' = (b_g @ Lg_w + Lg_b) * s_g.  s_z = log2(e), s_h = 2*log2(e)
// (folding the exp2 argument scale).  R gate is dead code: dropped.
// ---------------------------------------------------------------------------
__global__ __launch_bounds__(256) void precomp_kernel(
    const float* __restrict__ W_z, const float* __restrict__ b_z,
    const float* __restrict__ W_h, const float* __restrict__ b_h,
    const float* __restrict__ Lz_w, const float* __restrict__ Lz_b,
    const float* __restrict__ Lh_w, const float* __restrict__ Lh_b,
    float* __restrict__ ws)
{
    int t = threadIdx.x;
    for (int idx = t; idx < 512; idx += 256) {
        int g = idx >> 8;          // 0 = z, 1 = h
        int d = (idx >> 6) & 3;
        int j = idx & 63;
        const float* W  = g ? W_h  : W_z;
        const float* Lw = g ? Lh_w : Lz_w;
        float acc = 0.f;
        for (int h = 0; h < 64; ++h)
            acc += W[d * 64 + h] * Lw[h * 64 + j];
        ws[WS_GW + g * 256 + d * 64 + j] = acc * (g ? 2.f * L2E : L2E);
    }
    if (t < 128) {
        int g = t >> 6;
        int j = t & 63;
        const float* bg = g ? b_h  : b_z;
        const float* Lw = g ? Lh_w : Lz_w;
        const float* Lb = g ? Lh_b : Lz_b;
        float acc = Lb[j];
        for (int h = 0; h < 64; ++h)
            acc += bg[h] * Lw[h * 64 + j];
        ws[WS_GB + g * 64 + j] = acc * (g ? 2.f * L2E : L2E);
    }
}

// ---------------------------------------------------------------------------
// Kernel 1: one block of 256 threads per (b,l). Each thread serves TWO agent
// rows (r and r+64) and one column-quarter q (columns e = 4k+q): every LDS
// read of xe / xs feeds both rows, halving ds_read_b128 traffic (the round-9
// bottleneck: LDS instruction throughput, ~12 cyc per ds_read_b128).
// The 64 pairwise weights (32 per row) are cached in local arrays indexed
// ONLY by compile-time constants (fully unrolled loops) -> registers.
// launch_bounds(256,4) caps VGPR at 128 (~100 live) so no spill (r4 lesson).
// ---------------------------------------------------------------------------
__global__ __launch_bounds__(256, 4) void tgcn_kernel(
    const float* __restrict__ x,
    const float* __restrict__ ws_w,
    float* __restrict__ part)
{
    __shared__ float4 xr4_s[128];     // agent features
    __shared__ float4 xs4_s[128];     // dinv[e]*xr[e]
    __shared__ float4 M4_s[128];      // per-row m (pre-scaled by dinv[r])
    __shared__ float  gw_s[512];      // [g][d][64] prescaled gate weights
    __shared__ float  gb_s[128];      // [g][64] prescaled gate biases
    __shared__ float  red_s[4][64];

    const int t  = threadIdx.x;
    const int bl = blockIdx.x;

    // ---- stage ----
    if (t < 128) {
        xr4_s[t] = ((const float4*)(x + (size_t)bl * (A_ * D_)))[t];
        gb_s[t]  = ws_w[WS_GB + t];
    }
    gw_s[t]       = ws_w[WS_GW + t];
    gw_s[t + 256] = ws_w[WS_GW + t + 256];
    __syncthreads();

    const int r = t >> 2;           // row pair: rows r and r+64   (r in 0..63)
    const int q = t & 3;            // column-quarter (interleaved)

    const float4 xa0 = xr4_s[r];
    const float4 xa1 = xr4_s[r + 64];
    const v2 a0_01 = {xa0.x, xa0.y};
    const v2 a0_23 = {xa0.z, xa0.w};
    const v2 a1_01 = {xa1.x, xa1.y};
    const v2 a1_23 = {xa1.z, xa1.w};

    // ---- pass 1: pairwise weights for both rows -> reg arrays + rowsums ----
    float wu[32];                     // weights for row r
    float wv[32];                     // weights for row r+64
    float rsA0 = 0.f, rsA1 = 0.f, rsB0 = 0.f, rsB1 = 0.f;
    #pragma unroll
    for (int k = 0; k < 32; ++k) {
        float4 xe = xr4_s[(k << 2) | q];       // one read, two rows
        v2 e01 = {xe.x, xe.y};
        v2 e23 = {xe.z, xe.w};
        v2 dA01 = a0_01 - e01;
        v2 dA23 = a0_23 - e23;
        v2 sA = dA01 * dA01;
        sA = __builtin_elementwise_fma(dA23, dA23, sA);
        float wA = fminf(__builtin_amdgcn_rsqf(sA.x + sA.y), 1.0e6f);
        v2 dB01 = a1_01 - e01;
        v2 dB23 = a1_23 - e23;
        v2 sB = dB01 * dB01;
        sB = __builtin_elementwise_fma(dB23, dB23, sB);
        float wB = fminf(__builtin_amdgcn_rsqf(sB.x + sB.y), 1.0e6f);
        wu[k] = wA;
        wv[k] = wB;
        if (k & 1) { rsA1 += wA; rsB1 += wB; }
        else       { rsA0 += wA; rsB0 += wB; }
    }
    float rsA = rsA0 + rsA1;
    float rsB = rsB0 + rsB1;
    rsA += __shfl_xor(rsA, 1); rsA += __shfl_xor(rsA, 2);
    rsB += __shfl_xor(rsB, 1); rsB += __shfl_xor(rsB, 2);
    const float dinvA = __builtin_amdgcn_rsqf(rsA);
    const float dinvB = __builtin_amdgcn_rsqf(rsB);
    if (q == 0) {
        xs4_s[r]      = make_float4(dinvA * xa0.x, dinvA * xa0.y,
                                    dinvA * xa0.z, dinvA * xa0.w);
        xs4_s[r + 64] = make_float4(dinvB * xa1.x, dinvB * xa1.y,
                                    dinvB * xa1.z, dinvB * xa1.w);
    }
    __syncthreads();

    // ---- pass 2: m(row) = w_row . xs, one read feeds both rows ----
    v2 mA01 = {0.f, 0.f};
    v2 mA23 = {0.f, 0.f};
    v2 mB01 = {0.f, 0.f};
    v2 mB23 = {0.f, 0.f};
    #pragma unroll
    for (int k = 0; k < 32; ++k) {
        float4 xu = xr4_s[0];  // placeholder to keep type; overwritten below
        xu = xs4_s[(k << 2) | q];
        v2 u01 = {xu.x, xu.y};
        v2 u23 = {xu.z, xu.w};
        v2 wA2 = {wu[k], wu[k]};
        v2 wB2 = {wv[k], wv[k]};
        mA01 = __builtin_elementwise_fma(wA2, u01, mA01);
        mA23 = __builtin_elementwise_fma(wA2, u23, mA23);
        mB01 = __builtin_elementwise_fma(wB2, u01, mB01);
        mB23 = __builtin_elementwise_fma(wB2, u23, mB23);
    }
    float mA0 = mA01.x, mA1 = mA01.y, mA2 = mA23.x, mA3 = mA23.y;
    float mB0 = mB01.x, mB1 = mB01.y, mB2 = mB23.x, mB3 = mB23.y;
    mA0 += __shfl_xor(mA0, 1); mA0 += __shfl_xor(mA0, 2);
    mA1 += __shfl_xor(mA1, 1); mA1 += __shfl_xor(mA1, 2);
    mA2 += __shfl_xor(mA2, 1); mA2 += __shfl_xor(mA2, 2);
    mA3 += __shfl_xor(mA3, 1); mA3 += __shfl_xor(mA3, 2);
    mB0 += __shfl_xor(mB0, 1); mB0 += __shfl_xor(mB0, 2);
    mB1 += __shfl_xor(mB1, 1); mB1 += __shfl_xor(mB1, 2);
    mB2 += __shfl_xor(mB2, 1); mB2 += __shfl_xor(mB2, 2);
    mB3 += __shfl_xor(mB3, 1); mB3 += __shfl_xor(mB3, 2);
    if (q == 0) {
        M4_s[r]      = make_float4(dinvA * mA0, dinvA * mA1,
                                   dinvA * mA2, dinvA * mA3);
        M4_s[r + 64] = make_float4(dinvB * mB0, dinvB * mB1,
                                   dinvB * mB2, dinvB * mB3);
    }
    __syncthreads();

    // ---- gates, transposed: thread <-> column j, 32 agents per thread ----
    {
        const int j  = t & 63;
        const int g  = t >> 6;                 // wave id 0..3 -> agent group
        const v2 W0 = {gw_s[j],       gw_s[256 + j]};
        const v2 W1 = {gw_s[64 + j],  gw_s[320 + j]};
        const v2 W2 = {gw_s[128 + j], gw_s[384 + j]};
        const v2 W3 = {gw_s[192 + j], gw_s[448 + j]};
        const v2 Bzh = {gb_s[j], gb_s[64 + j]};
        float acc = 0.f;
        #pragma unroll
        for (int i = 0; i < 32; ++i) {
            float4 mv = M4_s[g * 32 + i];      // wave-uniform broadcast
            v2 zh = __builtin_elementwise_fma((v2){mv.x, mv.x}, W0, Bzh);
            zh = __builtin_elementwise_fma((v2){mv.y, mv.y}, W1, zh);
            zh = __builtin_elementwise_fma((v2){mv.z, mv.z}, W2, zh);
            zh = __builtin_elementwise_fma((v2){mv.w, mv.w}, W3, zh);
            float ez = __builtin_amdgcn_exp2f(zh.x);
            float e2 = __builtin_amdgcn_exp2f(zh.y);
            // (1-sigmoid)*tanh = (e2-1) / ((1+ez)*(1+e2)), one rcp
            float num = e2 - 1.f;
            float den = (1.f + ez) * (1.f + e2);
            float hv  = num * __builtin_amdgcn_rcpf(den);
            acc += fmaxf(hv, 0.f);
        }
        red_s[g][j] = acc;
    }
    __syncthreads();

    if (t < 64) {
        part[(size_t)bl * 64 + t] = red_s[0][t] + red_s[1][t]
                                  + red_s[2][t] + red_s[3][t];
    }
}

// ---------------------------------------------------------------------------
// Kernel 2: fused pool + decoder. One block of 1024 threads per batch.
// ---------------------------------------------------------------------------
__global__ __launch_bounds__(1024) void pooldec_kernel(
    const float* __restrict__ part,
    const float* __restrict__ D1_w, const float* __restrict__ D1_b,
    const float* __restrict__ D2_w, const float* __restrict__ D2_b,
    float* __restrict__ out)
{
    __shared__ float red_s[16][64];
    __shared__ float pooled_s[64];
    __shared__ float t1_s[256];
    const int t = threadIdx.x, b = blockIdx.x;

    // ---- pool over L: 16 groups x 16 rows ----
    {
        const int j = t & 63, g = t >> 6;
        const float* pb = part + ((size_t)b * L_ + g * 16) * 64;
        float s = 0.f;
        #pragma unroll
        for (int i = 0; i < 16; ++i) s += pb[i * 64 + j];
        red_s[g][j] = s;
    }
    __syncthreads();
    if (t < 64) {
        float s = 0.f;
        #pragma unroll
        for (int g = 0; g < 16; ++g) s += red_s[g][t];
        pooled_s[t] = s * (1.f / ((float)L_ * (float)A_));
    }
    __syncthreads();

    // ---- D1: 256 outputs, 4 threads per output (16 h each) ----
    {
        const int o = t >> 2, sub = t & 3;
        float acc = 0.f;
        #pragma unroll
        for (int hh = 0; hh < 16; ++hh) {
            int h = sub * 16 + hh;
            acc += pooled_s[h] * D1_w[h * 256 + o];
        }
        acc += __shfl_xor(acc, 1);
        acc += __shfl_xor(acc, 2);
        if (sub == 0) t1_s[o] = fmaxf(acc + D1_b[o], 0.f);
    }
    __syncthreads();

    // ---- D2: 512 outputs, 2 threads per output (128 k each) ----
    {
        const int o = t >> 1, kh = t & 1;
        float acc = 0.f;
        for (int kk = 0; kk < 128; ++kk) {
            int k = kh * 128 + kk;
            acc += t1_s[k] * D2_w[k * 512 + o];
        }
        acc += __shfl_xor(acc, 1);
        if (kh == 0) out[(size_t)b * 512 + o] = acc + D2_b[o];
    }
}

// ---------------------------------------------------------------------------
extern "C" void kernel_launch(void* const* d_in, const int* in_sizes, int n_in,
                              void* d_out, int out_size, void* d_ws, size_t ws_size,
                              hipStream_t stream)
{
    const float* x    = (const float*)d_in[0];
    // d_in[1..3]: x_mark_enc, x_dec, x_mark_dec — unused by the reference
    const float* W_z  = (const float*)d_in[4];
    const float* b_z  = (const float*)d_in[5];
    // d_in[6], d_in[7]: W_r, b_r — dead code in the reference
    const float* W_h  = (const float*)d_in[8];
    const float* b_h  = (const float*)d_in[9];
    const float* Lz_w = (const float*)d_in[10];
    const float* Lz_b = (const float*)d_in[11];
    // d_in[12], d_in[13]: Lr_w, Lr_b — dead
    const float* Lh_w = (const float*)d_in[14];
    const float* Lh_b = (const float*)d_in[15];
    const float* D1_w = (const float*)d_in[16];
    const float* D1_b = (const float*)d_in[17];
    const float* D2_w = (const float*)d_in[18];
    const float* D2_b = (const float*)d_in[19];

    float* ws  = (float*)d_ws;
    float* out = (float*)d_out;

    precomp_kernel<<<1, 256, 0, stream>>>(W_z, b_z, W_h, b_h,
                                          Lz_w, Lz_b, Lh_w, Lh_b, ws);
    tgcn_kernel<<<B_ * L_, 256, 0, stream>>>(x, ws, ws + WS_PART);
    pooldec_kernel<<<B_, 1024, 0, stream>>>(ws + WS_PART, D1_w, D1_b,
                                            D2_w, D2_b, out);
}

// Round 12
// 69.563 us; speedup vs baseline: 1.1490x; 1.1490x over previous
//
#include <hip/hip_runtime.h>
#include <hip/hip_bf16.h>
#include <math.h>

// Problem constants (match reference)
#define B_ 16
#define L_ 256
#define A_ 128
#define D_ 4
#define H_ 64
#define DFF_ 256
#define PRED_ 64
#define COUT_ 8

// ws layout (floats)
// gate weights SoA, exp2-prescaled: [g][d][64], g=0:z (x L2E), g=1:h (x 2*L2E)
#define WS_GW   0
// gate biases, same prescale: [g][64]
#define WS_GB   512
#define WS_PART 640                       // [B*L][64] per-(b,l) agent-sums

#define L2E 1.4426950408889634f

typedef float v2 __attribute__((ext_vector_type(2)));

// ---------------------------------------------------------------------------
// Kernel 0: fold gate weights. Wg' = (W_g @ Lg_w[0:64,:]) * s_g, stored SoA
// [d][j]; bg' = (b_g @ Lg_w + Lg_b) * s_g.  s_z = log2(e), s_h = 2*log2(e)
// (folding the exp2 argument scale).  R gate is dead code: dropped.
// ---------------------------------------------------------------------------
__global__ __launch_bounds__(256) void precomp_kernel(
    const float* __restrict__ W_z, const float* __restrict__ b_z,
    const float* __restrict__ W_h, const float* __restrict__ b_h,
    const float* __restrict__ Lz_w, const float* __restrict__ Lz_b,
    const float* __restrict__ Lh_w, const float* __restrict__ Lh_b,
    float* __restrict__ ws)
{
    int t = threadIdx.x;
    for (int idx = t; idx < 512; idx += 256) {
        int g = idx >> 8;          // 0 = z, 1 = h
        int d = (idx >> 6) & 3;
        int j = idx & 63;
        const float* W  = g ? W_h  : W_z;
        const float* Lw = g ? Lh_w : Lz_w;
        float acc = 0.f;
        for (int h = 0; h < 64; ++h)
            acc += W[d * 64 + h] * Lw[h * 64 + j];
        ws[WS_GW + g * 256 + d * 64 + j] = acc * (g ? 2.f * L2E : L2E);
    }
    if (t < 128) {
        int g = t >> 6;
        int j = t & 63;
        const float* bg = g ? b_h  : b_z;
        const float* Lw = g ? Lh_w : Lz_w;
        const float* Lb = g ? Lh_b : Lz_b;
        float acc = Lb[j];
        for (int h = 0; h < 64; ++h)
            acc += bg[h] * Lw[h * 64 + j];
        ws[WS_GB + g * 64 + j] = acc * (g ? 2.f * L2E : L2E);
    }
}

// ---------------------------------------------------------------------------
// Kernel 1: one block of 256 threads per (b,l). Each thread serves TWO agent
// rows (r and r+64) and one column-quarter q (columns e = 4k+q): every LDS
// read of xe / xs feeds both rows, halving ds_read_b128 traffic (the round-9
// bottleneck: LDS instruction throughput, ~12 cyc per ds_read_b128).
// The 64 pairwise weights (32 per row) are cached in local arrays indexed
// ONLY by compile-time constants (fully unrolled loops) -> registers.
// __launch_bounds__(256,3): the ONE proven no-spill config for a 64-float
// register cache (round 3: VGPR=76, zero scratch). (256,4) made the
// allocator target the 64-VGPR tier and spill 90 MB (round 11).
// ---------------------------------------------------------------------------
__global__ __launch_bounds__(256, 3) void tgcn_kernel(
    const float* __restrict__ x,
    const float* __restrict__ ws_w,
    float* __restrict__ part)
{
    __shared__ float4 xr4_s[128];     // agent features
    __shared__ float4 xs4_s[128];     // dinv[e]*xr[e]
    __shared__ float4 M4_s[128];      // per-row m (pre-scaled by dinv[r])
    __shared__ float  gw_s[512];      // [g][d][64] prescaled gate weights
    __shared__ float  gb_s[128];      // [g][64] prescaled gate biases
    __shared__ float  red_s[4][64];

    const int t  = threadIdx.x;
    const int bl = blockIdx.x;

    // ---- stage ----
    if (t < 128) {
        xr4_s[t] = ((const float4*)(x + (size_t)bl * (A_ * D_)))[t];
        gb_s[t]  = ws_w[WS_GB + t];
    }
    gw_s[t]       = ws_w[WS_GW + t];
    gw_s[t + 256] = ws_w[WS_GW + t + 256];
    __syncthreads();

    const int r = t >> 2;           // row pair: rows r and r+64   (r in 0..63)
    const int q = t & 3;            // column-quarter (interleaved)

    const float4 xa0 = xr4_s[r];
    const float4 xa1 = xr4_s[r + 64];
    const v2 a0_01 = {xa0.x, xa0.y};
    const v2 a0_23 = {xa0.z, xa0.w};
    const v2 a1_01 = {xa1.x, xa1.y};
    const v2 a1_23 = {xa1.z, xa1.w};

    // ---- pass 1: pairwise weights for both rows -> reg arrays + rowsums ----
    float wu[32];                     // weights for row r
    float wv[32];                     // weights for row r+64
    float rsA0 = 0.f, rsA1 = 0.f, rsB0 = 0.f, rsB1 = 0.f;
    #pragma unroll
    for (int k = 0; k < 32; ++k) {
        float4 xe = xr4_s[(k << 2) | q];       // one read, two rows
        v2 e01 = {xe.x, xe.y};
        v2 e23 = {xe.z, xe.w};
        v2 dA01 = a0_01 - e01;
        v2 dA23 = a0_23 - e23;
        v2 sA = dA01 * dA01;
        sA = __builtin_elementwise_fma(dA23, dA23, sA);
        float wA = fminf(__builtin_amdgcn_rsqf(sA.x + sA.y), 1.0e6f);
        v2 dB01 = a1_01 - e01;
        v2 dB23 = a1_23 - e23;
        v2 sB = dB01 * dB01;
        sB = __builtin_elementwise_fma(dB23, dB23, sB);
        float wB = fminf(__builtin_amdgcn_rsqf(sB.x + sB.y), 1.0e6f);
        wu[k] = wA;
        wv[k] = wB;
        if (k & 1) { rsA1 += wA; rsB1 += wB; }
        else       { rsA0 += wA; rsB0 += wB; }
    }
    float rsA = rsA0 + rsA1;
    float rsB = rsB0 + rsB1;
    rsA += __shfl_xor(rsA, 1); rsA += __shfl_xor(rsA, 2);
    rsB += __shfl_xor(rsB, 1); rsB += __shfl_xor(rsB, 2);
    const float dinvA = __builtin_amdgcn_rsqf(rsA);
    const float dinvB = __builtin_amdgcn_rsqf(rsB);
    if (q == 0) {
        xs4_s[r]      = make_float4(dinvA * xa0.x, dinvA * xa0.y,
                                    dinvA * xa0.z, dinvA * xa0.w);
        xs4_s[r + 64] = make_float4(dinvB * xa1.x, dinvB * xa1.y,
                                    dinvB * xa1.z, dinvB * xa1.w);
    }
    __syncthreads();

    // ---- pass 2: m(row) = w_row . xs, one read feeds both rows ----
    v2 mA01 = {0.f, 0.f};
    v2 mA23 = {0.f, 0.f};
    v2 mB01 = {0.f, 0.f};
    v2 mB23 = {0.f, 0.f};
    #pragma unroll
    for (int k = 0; k < 32; ++k) {
        float4 xu = xs4_s[(k << 2) | q];
        v2 u01 = {xu.x, xu.y};
        v2 u23 = {xu.z, xu.w};
        v2 wA2 = {wu[k], wu[k]};
        v2 wB2 = {wv[k], wv[k]};
        mA01 = __builtin_elementwise_fma(wA2, u01, mA01);
        mA23 = __builtin_elementwise_fma(wA2, u23, mA23);
        mB01 = __builtin_elementwise_fma(wB2, u01, mB01);
        mB23 = __builtin_elementwise_fma(wB2, u23, mB23);
    }
    float mA0 = mA01.x, mA1 = mA01.y, mA2 = mA23.x, mA3 = mA23.y;
    float mB0 = mB01.x, mB1 = mB01.y, mB2 = mB23.x, mB3 = mB23.y;
    mA0 += __shfl_xor(mA0, 1); mA0 += __shfl_xor(mA0, 2);
    mA1 += __shfl_xor(mA1, 1); mA1 += __shfl_xor(mA1, 2);
    mA2 += __shfl_xor(mA2, 1); mA2 += __shfl_xor(mA2, 2);
    mA3 += __shfl_xor(mA3, 1); mA3 += __shfl_xor(mA3, 2);
    mB0 += __shfl_xor(mB0, 1); mB0 += __shfl_xor(mB0, 2);
    mB1 += __shfl_xor(mB1, 1); mB1 += __shfl_xor(mB1, 2);
    mB2 += __shfl_xor(mB2, 1); mB2 += __shfl_xor(mB2, 2);
    mB3 += __shfl_xor(mB3, 1); mB3 += __shfl_xor(mB3, 2);
    if (q == 0) {
        M4_s[r]      = make_float4(dinvA * mA0, dinvA * mA1,
                                   dinvA * mA2, dinvA * mA3);
        M4_s[r + 64] = make_float4(dinvB * mB0, dinvB * mB1,
                                   dinvB * mB2, dinvB * mB3);
    }
    __syncthreads();

    // ---- gates, transposed: thread <-> column j, 32 agents per thread ----
    {
        const int j  = t & 63;
        const int g  = t >> 6;                 // wave id 0..3 -> agent group
        const v2 W0 = {gw_s[j],       gw_s[256 + j]};
        const v2 W1 = {gw_s[64 + j],  gw_s[320 + j]};
        const v2 W2 = {gw_s[128 + j], gw_s[384 + j]};
        const v2 W3 = {gw_s[192 + j], gw_s[448 + j]};
        const v2 Bzh = {gb_s[j], gb_s[64 + j]};
        float acc = 0.f;
        #pragma unroll
        for (int i = 0; i < 32; ++i) {
            float4 mv = M4_s[g * 32 + i];      // wave-uniform broadcast
            v2 zh = __builtin_elementwise_fma((v2){mv.x, mv.x}, W0, Bzh);
            zh = __builtin_elementwise_fma((v2){mv.y, mv.y}, W1, zh);
            zh = __builtin_elementwise_fma((v2){mv.z, mv.z}, W2, zh);
            zh = __builtin_elementwise_fma((v2){mv.w, mv.w}, W3, zh);
            float ez = __builtin_amdgcn_exp2f(zh.x);
            float e2 = __builtin_amdgcn_exp2f(zh.y);
            // (1-sigmoid)*tanh = (e2-1) / ((1+ez)*(1+e2)), one rcp
            float num = e2 - 1.f;
            float den = (1.f + ez) * (1.f + e2);
            float hv  = num * __builtin_amdgcn_rcpf(den);
            acc += fmaxf(hv, 0.f);
        }
        red_s[g][j] = acc;
    }
    __syncthreads();

    if (t < 64) {
        part[(size_t)bl * 64 + t] = red_s[0][t] + red_s[1][t]
                                  + red_s[2][t] + red_s[3][t];
    }
}

// ---------------------------------------------------------------------------
// Kernel 2: fused pool + decoder. One block of 1024 threads per batch.
// ---------------------------------------------------------------------------
__global__ __launch_bounds__(1024) void pooldec_kernel(
    const float* __restrict__ part,
    const float* __restrict__ D1_w, const float* __restrict__ D1_b,
    const float* __restrict__ D2_w, const float* __restrict__ D2_b,
    float* __restrict__ out)
{
    __shared__ float red_s[16][64];
    __shared__ float pooled_s[64];
    __shared__ float t1_s[256];
    const int t = threadIdx.x, b = blockIdx.x;

    // ---- pool over L: 16 groups x 16 rows ----
    {
        const int j = t & 63, g = t >> 6;
        const float* pb = part + ((size_t)b * L_ + g * 16) * 64;
        float s = 0.f;
        #pragma unroll
        for (int i = 0; i < 16; ++i) s += pb[i * 64 + j];
        red_s[g][j] = s;
    }
    __syncthreads();
    if (t < 64) {
        float s = 0.f;
        #pragma unroll
        for (int g = 0; g < 16; ++g) s += red_s[g][t];
        pooled_s[t] = s * (1.f / ((float)L_ * (float)A_));
    }
    __syncthreads();

    // ---- D1: 256 outputs, 4 threads per output (16 h each) ----
    {
        const int o = t >> 2, sub = t & 3;
        float acc = 0.f;
        #pragma unroll
        for (int hh = 0; hh < 16; ++hh) {
            int h = sub * 16 + hh;
            acc += pooled_s[h] * D1_w[h * 256 + o];
        }
        acc += __shfl_xor(acc, 1);
        acc += __shfl_xor(acc, 2);
        if (sub == 0) t1_s[o] = fmaxf(acc + D1_b[o], 0.f);
    }
    __syncthreads();

    // ---- D2: 512 outputs, 2 threads per output (128 k each) ----
    {
        const int o = t >> 1, kh = t & 1;
        float acc = 0.f;
        for (int kk = 0; kk < 128; ++kk) {
            int k = kh * 128 + kk;
            acc += t1_s[k] * D2_w[k * 512 + o];
        }
        acc += __shfl_xor(acc, 1);
        if (kh == 0) out[(size_t)b * 512 + o] = acc + D2_b[o];
    }
}

// ---------------------------------------------------------------------------
extern "C" void kernel_launch(void* const* d_in, const int* in_sizes, int n_in,
                              void* d_out, int out_size, void* d_ws, size_t ws_size,
                              hipStream_t stream)
{
    const float* x    = (const float*)d_in[0];
    // d_in[1..3]: x_mark_enc, x_dec, x_mark_dec — unused by the reference
    const float* W_z  = (const float*)d_in[4];
    const float* b_z  = (const float*)d_in[5];
    // d_in[6], d_in[7]: W_r, b_r — dead code in the reference
    const float* W_h  = (const float*)d_in[8];
    const float* b_h  = (const float*)d_in[9];
    const float* Lz_w = (const float*)d_in[10];
    const float* Lz_b = (const float*)d_in[11];
    // d_in[12], d_in[13]: Lr_w, Lr_b — dead
    const float* Lh_w = (const float*)d_in[14];
    const float* Lh_b = (const float*)d_in[15];
    const float* D1_w = (const float*)d_in[16];
    const float* D1_b = (const float*)d_in[17];
    const float* D2_w = (const float*)d_in[18];
    const float* D2_b = (const float*)d_in[19];

    float* ws  = (float*)d_ws;
    float* out = (float*)d_out;

    precomp_kernel<<<1, 256, 0, stream>>>(W_z, b_z, W_h, b_h,
                                          Lz_w, Lz_b, Lh_w, Lh_b, ws);
    tgcn_kernel<<<B_ * L_, 256, 0, stream>>>(x, ws, ws + WS_PART);
    pooldec_kernel<<<B_, 1024, 0, stream>>>(ws + WS_PART, D1_w, D1_b,
                                            D2_w, D2_b, out);
}